// Round 12
// baseline (148.528 us; speedup 1.0000x reference)
//
#include <hip/hip_runtime.h>
#include <math.h>

#define NRAY2 4096
#define NSAMP 64
#define PHD 192
#define PLANE (PHD*PHD)          // 36864
constexpr float STEP = 1.0f / 63.0f;

struct Mats { float crd[16]; float drv[16]; };

// ---------------- host-side constant matrices (replicates numpy fp64 math) ---
static void mat_mul4(const double* A, const double* B, double* C) {
    for (int i = 0; i < 4; ++i)
        for (int j = 0; j < 4; ++j) {
            double s = 0.0;
            for (int k = 0; k < 4; ++k) s += A[i*4+k] * B[k*4+j];
            C[i*4+j] = s;
        }
}

static void build_mats(Mats& M) {
    const double tx = 0.1, ty = 0.05, tz = 0.02;
    const double cx = 0.5, cy = 0.5, cz = 0.5;
    auto ry = [](double t, double* m) {
        double c = cos(t), s = sin(t);
        double v[16] = {1,0,0,0, 0,c,-s,0, 0,s,c,0, 0,0,0,1};
        for (int i = 0; i < 16; ++i) m[i] = v[i];
    };
    auto rx = [](double t, double* m) {
        double c = cos(t), s = sin(t);
        double v[16] = {c,0,-s,0, 0,1,0,0, s,0,c,0, 0,0,0,1};
        for (int i = 0; i < 16; ++i) m[i] = v[i];
    };
    auto rz = [](double t, double* m) {
        double c = cos(t), s = sin(t);
        double v[16] = {c,-s,0,0, s,c,0,0, 0,0,1,0, 0,0,0,1};
        for (int i = 0; i < 16; ++i) m[i] = v[i];
    };
    double RY[16], RY_[16], RX[16], RX_[16], RZ[16], RZ_[16];
    ry(-ty, RY); ry(ty, RY_);
    rx(tx, RX);  rx(-tx, RX_);
    rz(-tz, RZ); rz(tz, RZ_);
    double S1[16] = {1,0,0,0, 0,1,0,0, 0,0,1,0, -cx,-cy,-cz,1};
    double S2[16] = {1,0,0,0, 0,1,0,0, 0,0,1,0,  cx, cy, cz,1};
    double t1[16], t2[16], t3[16], Mc[16], Md[16];
    mat_mul4(S1, RZ, t1);
    mat_mul4(t1, RY, t2);
    mat_mul4(t2, RX, t3);
    mat_mul4(t3, S2, Mc);
    mat_mul4(RX_, RY_, t1);
    mat_mul4(t1, RZ_, Md);
    for (int i = 0; i < 16; ++i) { M.crd[i] = (float)Mc[i]; M.drv[i] = (float)Md[i]; }
}

// One butterfly level applied to all 8 values (chains overlap).
template<int CTRL>
__device__ __forceinline__ void dpp_level8(float* v) {
    int t[8];
    #pragma unroll
    for (int i = 0; i < 8; ++i)
        t[i] = __builtin_amdgcn_update_dpp(0, __float_as_int(v[i]), CTRL, 0xF, 0xF, true);
    #pragma unroll
    for (int i = 0; i < 8; ++i) v[i] += __int_as_float(t[i]);
}

// 8-lane allreduce of 8 values in 3 pure-DPP levels:
//  quad_perm [1,0,3,2] (xor-1), quad_perm [2,3,0,1] (xor-2), then
//  row_half_mirror (after the first two levels every quad lane holds the
//  quad sum, so mirror across the 8-half is a valid 3rd butterfly level).
__device__ __forceinline__ void red8_8(float* v) {
    dpp_level8<0xB1>(v);    // quad_perm 1,0,3,2
    dpp_level8<0x4E>(v);    // quad_perm 2,3,0,1
    dpp_level8<0x141>(v);   // row_half_mirror
}

// ---------------- kernel 1: ray tracing -------------------------------------
// R12: 8 lanes per ray x 4 neighbors per lane (ILP-4). At 1 wave/SIMD the
// wall is 63 x chain-latency; 4 independent Gaussian chains per thread hide
// dependent-VALU latency inside each step and the reduction shrinks to 3 DPP
// levels. 8 rays/wave, 512 single-wave blocks. Keeps: LDS mesh buffer +
// bulk writeout (R9), loads-only vmcnt queue, exp2 constant fold.
__global__ __launch_bounds__(64, 1) void ray_trace_kernel(
    const float* __restrict__ RI,       // (64^3, 2) interleaved [A, sig]
    const float* __restrict__ RayInit,  // (4096, 5)
    float* __restrict__ meshXT,         // (64, 4096)  stores 2X-1
    float* __restrict__ meshYT,         // (64, 4096)  stores 2Y-1
    Mats M)
{
    __shared__ float lX[NSAMP][8];      // [s][ray_local]  2 KB
    __shared__ float lY[NSAMP][8];      // 2 KB

    const int tid = threadIdx.x;
    const int nb  = tid & 7;                         // lane within 8-group
    const int rl  = tid >> 3;                        // ray local 0..7
    const int ray = blockIdx.x * 8 + rl;

    float xr[4], yr[4], zr[4];
    bool  act[4];
    #pragma unroll
    for (int k = 0; k < 4; ++k) {
        int n = nb + 8*k;
        act[k] = (n < 27);
        int nn = act[k] ? n : 0;
        xr[k] = (float)((nn/3)%3 - 1);
        yr[k] = (float)(nn/9 - 1);
        zr[k] = (float)(nn%3 - 1);
    }

    float X  = RayInit[ray*5 + 0];
    float dX = RayInit[ray*5 + 1];
    float Y  = RayInit[ray*5 + 2];
    float dY = RayInit[ray*5 + 3];
    float z  = RayInit[ray*5 + 4];

    if (nb == 0) { lX[0][rl] = X*2.0f - 1.0f; lY[0][rl] = Y*2.0f - 1.0f; }

    // transform + 4 neighbor cells: issues 4 gathers, returns dx/dy/dz per k
    auto prep = [&](float pX, float pY, float pz,
                    float* dxo, float* dyo, float* dzo, float2* rio) {
        float x  = pY*M.crd[1] + pX*M.crd[5] + pz*M.crd[9]  + M.crd[13];
        float y  = pY*M.crd[0] + pX*M.crd[4] + pz*M.crd[8]  + M.crd[12];
        float zz = pY*M.crd[2] + pX*M.crd[6] + pz*M.crd[10] + M.crd[14];
        float rx_ = rintf(x*64.0f), ry_ = rintf(y*64.0f), rz_ = rintf(zz*64.0f);
        #pragma unroll
        for (int k = 0; k < 4; ++k) {
            float Xn = __builtin_amdgcn_fmed3f(rx_ + xr[k], 0.0f, 63.0f);
            float Yn = __builtin_amdgcn_fmed3f(ry_ + yr[k], 0.0f, 63.0f);
            float Zn = __builtin_amdgcn_fmed3f(rz_ + zr[k], 0.0f, 63.0f);
            int lin = (int)(Yn*4096.0f + Xn*64.0f + Zn);   // exact in fp32
            rio[k] = ((const float2*)RI)[lin];
            dxo[k] = Xn*(1.0f/63.0f) - x;
            dyo[k] = Yn*(1.0f/63.0f) - y;
            dzo[k] = Zn*(1.0f/63.0f) - zz;
        }
    };

    float dxA[4], dyA[4], dzA[4];
    float2 riA[4];
    prep(X, Y, z, dxA, dyA, dzA, riA);

    // v_exp_f32 computes 2^x: fold -0.5*log2(e) into the Gaussian constant.
    const float C = -0.72134752044448169f;   // -0.5 * log2(e)

    for (int s = 1; s < NSAMP; ++s) {
        // one-step-ahead prefetch (position uses only pre-reduction state)
        float nX = X + dX*STEP, nY = Y + dY*STEP, nz = z + STEP;
        float dxB[4], dyB[4], dzB[4];
        float2 riB[4];
        prep(nX, nY, nz, dxB, dyB, dzB, riB);

        // 4 independent Gaussian chains (ILP-4), summed locally
        float v[8] = {0,0,0,0,0,0,0,0};
        #pragma unroll
        for (int k = 0; k < 4; ++k) {
            float is = __builtin_amdgcn_rcpf(riA[k].y * riA[k].y);
            float d2 = dxA[k]*dxA[k] + dyA[k]*dyA[k] + dzA[k]*dzA[k];
            float e  = __builtin_amdgcn_exp2f(d2 * is * C) + 2e-7f;
            if (!act[k]) e = 0.0f;
            float gx = dxA[k]*is, gy = dyA[k]*is, gz = dzA[k]*is;
            float nu = e * riA[k].x;
            v[0] += e;
            v[1] += nu;
            v[2] += nu*gx;  v[3] += nu*gy;  v[4] += nu*gz;
            v[5] += e*gx;   v[6] += e*gy;   v[7] += e*gz;
        }
        red8_8(v);
        float ni  = v[0], nuA = v[1];
        float sx  = v[2], sy  = v[3], sz  = v[4];
        float sdx = v[5], sdy = v[6], sdz = v[7];

        float r   = __builtin_amdgcn_rcpf(ni);
        float rn  = ni * __builtin_amdgcn_rcpf(nuA);   // 1/n = norm/nu_s
        float in2 = r * r;
        float gx_ = (ni*sx - nuA*sdx) * in2;
        float gy_ = (ni*sy - nuA*sdy) * in2;
        float gz_ = (ni*sz - nuA*sdz) * in2;

        float dndx = gy_*M.drv[1] + gx_*M.drv[5] + gz_*M.drv[9]  + M.drv[13];
        float dndy = gy_*M.drv[0] + gx_*M.drv[4] + gz_*M.drv[8]  + M.drv[12];
        float dndz = gy_*M.drv[2] + gx_*M.drv[6] + gz_*M.drv[10] + M.drv[14];

        float dX2 = (dndx - dndz*dX) * (1.0f + dX*dX) * rn;
        float dY2 = (dndy - dndz*dY) * (1.0f + dY*dY) * rn;

        X = nX; Y = nY; z = nz;
        dX += dX2 * STEP;
        dY += dY2 * STEP;

        // LDS buffer instead of global store: keeps vmcnt queue loads-only
        if (nb == 0) { lX[s][rl] = X*2.0f - 1.0f; lY[s][rl] = Y*2.0f - 1.0f; }

        #pragma unroll
        for (int k = 0; k < 4; ++k) {
            dxA[k] = dxB[k]; dyA[k] = dyB[k]; dzA[k] = dzB[k];
            riA[k] = riB[k];
        }
    }

    __syncthreads();   // single wave: cheap; orders ds_writes before reads

    // bulk writeout: lane s stores this block's 8 rays (two float4 each)
    {
        const int s = tid;                     // 0..63
        const int ray0 = blockIdx.x * 8;
        *(float4*)&meshXT[s*NRAY2 + ray0]     = *(const float4*)&lX[s][0];
        *(float4*)&meshXT[s*NRAY2 + ray0 + 4] = *(const float4*)&lX[s][4];
        *(float4*)&meshYT[s*NRAY2 + ray0]     = *(const float4*)&lY[s][0];
        *(float4*)&meshYT[s*NRAY2 + ray0 + 4] = *(const float4*)&lY[s][4];
    }
}

// ---------------- kernel 2: fused resize + grid sample ----------------------
// Pack-of-4 version (unchanged from R8).
typedef _Float16 h16;
typedef _Float16 h16v4 __attribute__((ext_vector_type(4)));

__global__ __launch_bounds__(1024) void sample_kernel(
    const float* __restrict__ vol,      // 192^3
    const float* __restrict__ meshXT,   // (64, 4096)
    const float* __restrict__ meshYT,
    h16*   __restrict__ outTh,          // fp16 transposed out [c][a*192+b]
    float* __restrict__ outDirect,      // fallback fp32 out [a][b][c]
    int transposed)
{
    __shared__ h16    plane_h[PLANE];     // 73,728 B
    __shared__ float2 slice[64*64];       // 32,768 B

    const int tid = threadIdx.x;
    const int blk = blockIdx.x;
    const int c = (blk >> 3) + 24 * (blk & 7);   // consecutive c on same XCD

    const float D = 63.0f / 191.0f;

    {
        const float4* src = (const float4*)(vol + c * PLANE);
        h16v4* dst = (h16v4*)plane_h;
        #pragma unroll
        for (int k = 0; k < (PLANE/4)/1024; ++k) {
            float4 v = src[tid + k*1024];
            h16v4 hv = {(h16)v.x, (h16)v.y, (h16)v.z, (h16)v.w};
            dst[tid + k*1024] = hv;
        }
    }

    float ps = c * D;
    int s0 = min((int)ps, 62);
    float wcs = ps - (float)s0, wc0 = 1.0f - wcs;
    {
        const float* x0 = meshXT + s0*NRAY2;
        const float* x1 = meshXT + (s0+1)*NRAY2;
        const float* y0 = meshYT + s0*NRAY2;
        const float* y1 = meshYT + (s0+1)*NRAY2;
        #pragma unroll
        for (int k = 0; k < 4096/1024; ++k) {
            int t = tid + k*1024;
            slice[t] = make_float2(x0[t]*wc0 + x1[t]*wcs,
                                   y0[t]*wc0 + y1[t]*wcs);
        }
    }
    __syncthreads();

    #pragma unroll 1
    for (int k = 0; k < PLANE/4096; ++k) {        // 9 iterations
        const int w0 = (tid + k*1024) * 4;        // linear within plane
        const int a  = w0 / PHD;                  // pack stays in one row
        const int b0 = w0 - a*PHD;

        float pa = (float)a * D;
        int   i0 = min((int)pa, 62);
        float wa = pa - (float)i0;

        float pb0 = (float)b0 * D;
        int  jmin = min((int)pb0, 62);
        int  j2   = min(jmin + 2, 63);

        float2 r0c0 = slice[i0*64 + jmin];
        float2 r0c1 = slice[i0*64 + jmin + 1];
        float2 r0c2 = slice[i0*64 + j2];
        float2 r1c0 = slice[(i0+1)*64 + jmin];
        float2 r1c1 = slice[(i0+1)*64 + jmin + 1];
        float2 r1c2 = slice[(i0+1)*64 + j2];

        float c0x = r0c0.x + wa*(r1c0.x - r0c0.x);
        float c0y = r0c0.y + wa*(r1c0.y - r0c0.y);
        float c1x = r0c1.x + wa*(r1c1.x - r0c1.x);
        float c1y = r0c1.y + wa*(r1c1.y - r0c1.y);
        float c2x = r0c2.x + wa*(r1c2.x - r0c2.x);
        float c2y = r0c2.y + wa*(r1c2.y - r0c2.y);

        h16v4 res;
        #pragma unroll
        for (int m = 0; m < 4; ++m) {
            float pb = (float)(b0 + m) * D;
            int   j0 = min((int)pb, 62);
            float wb = pb - (float)j0;
            bool  hi = (j0 != jmin);

            float sax = hi ? c1x : c0x, say = hi ? c1y : c0y;
            float sbx = hi ? c2x : c1x, sby = hi ? c2y : c1y;
            float gx = sax + wb*(sbx - sax);
            float gy = say + wb*(sby - say);

            float ix = (gx + 1.0f) * 0.5f * 191.0f;
            float iy = (gy + 1.0f) * 0.5f * 191.0f;
            float x0f = floorf(ix); float fx = ix - x0f;
            float y0f = floorf(iy); float fy = iy - y0f;

            float acc = 0.0f;
            #pragma unroll
            for (int dyy = 0; dyy < 2; ++dyy) {
                #pragma unroll
                for (int dxx = 0; dxx < 2; ++dxx) {
                    float xi = x0f + (float)dxx;
                    float yi = y0f + (float)dyy;
                    bool inb = (xi >= 0.0f) && (xi <= 191.0f) &&
                               (yi >= 0.0f) && (yi <= 191.0f);
                    int xc = min(max((int)xi, 0), PHD - 1);
                    int yc = min(max((int)yi, 0), PHD - 1);
                    float w = (dxx ? fx : 1.0f - fx) * (dyy ? fy : 1.0f - fy);
                    float val = (float)plane_h[yc*PHD + xc];
                    acc += inb ? w * val : 0.0f;
                }
            }
            res[m] = (h16)acc;
        }

        if (transposed) {
            *(h16v4*)(outTh + (size_t)c*PLANE + w0) = res;   // 8 B contiguous
        } else {
            #pragma unroll
            for (int m = 0; m < 4; ++m)
                outDirect[(size_t)(a*PHD + b0 + m)*PHD + c] = (float)res[m];
        }
    }
}

// ---------------- kernel 3: (b,c) tile transpose, fp16 -> fp32 --------------
__global__ __launch_bounds__(256) void transpose_kernel(
    const h16* __restrict__ outTh, float* __restrict__ out)
{
    __shared__ h16 t[64][66];
    const int a  = blockIdx.z;
    const int b0 = blockIdx.x * 64;
    const int c0 = blockIdx.y * 64;
    const int tx = threadIdx.x & 63;
    const int ty = threadIdx.x >> 6;     // 0..3

    const h16* src = outTh + (size_t)(c0 + ty) * PLANE + a*PHD + b0 + tx;
    #pragma unroll
    for (int j = 0; j < 16; ++j)
        t[ty + 4*j][tx] = src[(size_t)(4*j) * PLANE];
    __syncthreads();

    float* dst = out + (size_t)a * PLANE + (size_t)(b0 + ty) * PHD + c0 + tx;
    #pragma unroll
    for (int j = 0; j < 16; ++j)
        dst[(size_t)(4*j) * PHD] = (float)t[tx][ty + 4*j];
}

// ---------------- launch -----------------------------------------------------
extern "C" void kernel_launch(void* const* d_in, const int* in_sizes, int n_in,
                              void* d_out, int out_size, void* d_ws, size_t ws_size,
                              hipStream_t stream)
{
    const float* Phantom = (const float*)d_in[0];   // 192^3
    const float* RI      = (const float*)d_in[1];   // (64^3, 2)
    const float* RayInit = (const float*)d_in[2];   // (4096, 5)
    float* out = (float*)d_out;

    float* meshXT = (float*)d_ws;                   // (64, 4096)   1 MB
    float* meshYT = meshXT + NRAY2 * NSAMP;         // (64, 4096)   1 MB
    h16*   outTh  = (h16*)(meshYT + NRAY2 * NSAMP); // 192^3 fp16   14.2 MB

    const size_t need = (size_t)(2 * NRAY2 * NSAMP) * sizeof(float)
                      + (size_t)PHD * PLANE * sizeof(h16);
    const int use_transpose = (ws_size >= need) ? 1 : 0;

    Mats M;
    build_mats(M);

    ray_trace_kernel<<<NRAY2/8, 64, 0, stream>>>(RI, RayInit, meshXT, meshYT, M);

    if (use_transpose) {
        sample_kernel<<<PHD, 1024, 0, stream>>>(Phantom, meshXT, meshYT,
                                                outTh, nullptr, 1);
        transpose_kernel<<<dim3(3, 3, PHD), 256, 0, stream>>>(outTh, out);
    } else {
        sample_kernel<<<PHD, 1024, 0, stream>>>(Phantom, meshXT, meshYT,
                                                nullptr, out, 0);
    }
}

// Round 13
// 142.505 us; speedup vs baseline: 1.0423x; 1.0423x over previous
//
#include <hip/hip_runtime.h>
#include <math.h>

#define NRAY2 4096
#define NSAMP 64
#define PHD 192
#define PLANE (PHD*PHD)          // 36864
constexpr float STEP = 1.0f / 63.0f;

struct Mats { float crd[16]; float drv[16]; };

// ---------------- host-side constant matrices (replicates numpy fp64 math) ---
static void mat_mul4(const double* A, const double* B, double* C) {
    for (int i = 0; i < 4; ++i)
        for (int j = 0; j < 4; ++j) {
            double s = 0.0;
            for (int k = 0; k < 4; ++k) s += A[i*4+k] * B[k*4+j];
            C[i*4+j] = s;
        }
}

static void build_mats(Mats& M) {
    const double tx = 0.1, ty = 0.05, tz = 0.02;
    const double cx = 0.5, cy = 0.5, cz = 0.5;
    auto ry = [](double t, double* m) {
        double c = cos(t), s = sin(t);
        double v[16] = {1,0,0,0, 0,c,-s,0, 0,s,c,0, 0,0,0,1};
        for (int i = 0; i < 16; ++i) m[i] = v[i];
    };
    auto rx = [](double t, double* m) {
        double c = cos(t), s = sin(t);
        double v[16] = {c,0,-s,0, 0,1,0,0, s,0,c,0, 0,0,0,1};
        for (int i = 0; i < 16; ++i) m[i] = v[i];
    };
    auto rz = [](double t, double* m) {
        double c = cos(t), s = sin(t);
        double v[16] = {c,-s,0,0, s,c,0,0, 0,0,1,0, 0,0,0,1};
        for (int i = 0; i < 16; ++i) m[i] = v[i];
    };
    double RY[16], RY_[16], RX[16], RX_[16], RZ[16], RZ_[16];
    ry(-ty, RY); ry(ty, RY_);
    rx(tx, RX);  rx(-tx, RX_);
    rz(-tz, RZ); rz(tz, RZ_);
    double S1[16] = {1,0,0,0, 0,1,0,0, 0,0,1,0, -cx,-cy,-cz,1};
    double S2[16] = {1,0,0,0, 0,1,0,0, 0,0,1,0,  cx, cy, cz,1};
    double t1[16], t2[16], t3[16], Mc[16], Md[16];
    mat_mul4(S1, RZ, t1);
    mat_mul4(t1, RY, t2);
    mat_mul4(t2, RX, t3);
    mat_mul4(t3, S2, Mc);
    mat_mul4(RX_, RY_, t1);
    mat_mul4(t1, RZ_, Md);
    for (int i = 0; i < 16; ++i) { M.crd[i] = (float)Mc[i]; M.drv[i] = (float)Md[i]; }
}

// One butterfly level applied to all 8 values (chains overlap).
template<int CTRL>
__device__ __forceinline__ void dpp_level8(float* v) {
    int t[8];
    #pragma unroll
    for (int i = 0; i < 8; ++i)
        t[i] = __builtin_amdgcn_update_dpp(0, __float_as_int(v[i]), CTRL, 0xF, 0xF, true);
    #pragma unroll
    for (int i = 0; i < 8; ++i) v[i] += __int_as_float(t[i]);
}

// 16-lane allreduce of 8 values: 4 pure-DPP row_ror levels (proven R6-R11).
__device__ __forceinline__ void red8_16(float* v) {
    dpp_level8<0x121>(v);   // row_ror:1
    dpp_level8<0x122>(v);   // row_ror:2
    dpp_level8<0x124>(v);   // row_ror:4
    dpp_level8<0x128>(v);   // row_ror:8
}

// ---------------- kernel 1: ray tracing -------------------------------------
// R13: Z-triple restructure. The 27 neighbors = 9 (Y,X) pairs x 3 CONSECUTIVE
// Z (lin = 4096Y + 64X + Z). Lanes 0-8 (of 16 per ray) each own one (Y,X)
// pair: ONE address chain + 3 loads at immediate offsets (0/8/16 B), one
// shared dx/dy, ILP-3 Gaussian chains. Per-step VALU ~ -35%, TA line
// transactions ~ -2x vs the 27-independent-gather versions. Boundary Z
// handled by loading from Zb=clamp(rz-1,0,61) and selecting the 3 needed
// entries (exact for out-of-range rz too). Keeps R9 LDS mesh buffer + bulk
// writeout (loads-only vmcnt queue) and the exp2 constant fold.
__global__ __launch_bounds__(64, 1) void ray_trace_kernel(
    const float* __restrict__ RI,       // (64^3, 2) interleaved [A, sig]
    const float* __restrict__ RayInit,  // (4096, 5)
    float* __restrict__ meshXT,         // (64, 4096)  stores 2X-1
    float* __restrict__ meshYT,         // (64, 4096)  stores 2Y-1
    Mats M)
{
    __shared__ float lX[NSAMP][4];      // [s][ray_local]  1 KB
    __shared__ float lY[NSAMP][4];      // 1 KB

    const int tid = threadIdx.x;
    const int nb  = tid & 15;                        // lane within 16-row
    const int rl  = tid >> 4;                        // ray local 0..3
    const int ray = blockIdx.x * 4 + rl;
    const bool act = nb < 9;                         // 9 (Y,X) cells

    const int m9 = act ? nb : 0;
    const float yo = (float)(m9/3 - 1);
    const float xo = (float)(m9%3 - 1);

    float X  = RayInit[ray*5 + 0];
    float dX = RayInit[ray*5 + 1];
    float Y  = RayInit[ray*5 + 2];
    float dY = RayInit[ray*5 + 3];
    float z  = RayInit[ray*5 + 4];

    if (nb == 0) { lX[0][rl] = X*2.0f - 1.0f; lY[0][rl] = Y*2.0f - 1.0f; }

    // per-step prefetched state (one (Y,X) cell, 3 Z-entries)
    struct St {
        float dx, dy;            // shared over the Z-triple
        float dz0, dz1, dz2;     // per-Z offsets (post-clamp)
        float s1, s2;            // Zk - Zb selectors (0,1,2) for k=1,2
        float2 r0, r1, r2;       // raw loaded RI entries at Zb,Zb+1,Zb+2
    };

    auto prep = [&](float pX, float pY, float pz, St& st) {
        float x  = pY*M.crd[1] + pX*M.crd[5] + pz*M.crd[9]  + M.crd[13];
        float y  = pY*M.crd[0] + pX*M.crd[4] + pz*M.crd[8]  + M.crd[12];
        float zz = pY*M.crd[2] + pX*M.crd[6] + pz*M.crd[10] + M.crd[14];
        float rx_ = rintf(x*64.0f), ry_ = rintf(y*64.0f), rz_ = rintf(zz*64.0f);
        float Xn = __builtin_amdgcn_fmed3f(rx_ + xo, 0.0f, 63.0f);
        float Yn = __builtin_amdgcn_fmed3f(ry_ + yo, 0.0f, 63.0f);
        float Zb = __builtin_amdgcn_fmed3f(rz_ - 1.0f, 0.0f, 61.0f);
        float Z0 = __builtin_amdgcn_fmed3f(rz_ - 1.0f, 0.0f, 63.0f);
        float Z1 = __builtin_amdgcn_fmed3f(rz_,        0.0f, 63.0f);
        float Z2 = __builtin_amdgcn_fmed3f(rz_ + 1.0f, 0.0f, 63.0f);
        st.dx  = Xn*(1.0f/63.0f) - x;
        st.dy  = Yn*(1.0f/63.0f) - y;
        st.dz0 = Z0*(1.0f/63.0f) - zz;
        st.dz1 = Z1*(1.0f/63.0f) - zz;
        st.dz2 = Z2*(1.0f/63.0f) - zz;
        st.s1  = Z1 - Zb;                     // 0,1,2
        st.s2  = Z2 - Zb;
        int lin = (int)(Yn*4096.0f + Xn*64.0f + Zb);   // exact in fp32
        const float2* p = (const float2*)RI + lin;
        st.r0 = p[0];                          // 3 loads, immediate offsets
        st.r1 = p[1];
        st.r2 = p[2];
    };

    St A;
    prep(X, Y, z, A);

    // v_exp_f32 computes 2^x: fold -0.5*log2(e) into the Gaussian constant.
    const float C = -0.72134752044448169f;   // -0.5 * log2(e)

    for (int s = 1; s < NSAMP; ++s) {
        // one-step-ahead prefetch (position uses only pre-reduction state)
        float nX = X + dX*STEP, nY = Y + dY*STEP, nz = z + STEP;
        St B;
        prep(nX, nY, nz, B);

        // select the 3 (possibly clamp-duplicated) RI entries.
        // Z0: interior -> r0; only rz>=63 pushes Z0 to Zb+1.
        float2 ri0 = (A.s1 > 1.5f) ? A.r1 : A.r0;         // s1==2 iff rz>=63
        float2 ri1 = (A.s1 > 1.5f) ? A.r2 :
                     ((A.s1 > 0.5f) ? A.r1 : A.r0);
        float2 ri2 = (A.s2 > 1.5f) ? A.r2 :
                     ((A.s2 > 0.5f) ? A.r1 : A.r0);

        float v[8] = {0,0,0,0,0,0,0,0};
        float dzs[3] = {A.dz0, A.dz1, A.dz2};
        float2 ris[3] = {ri0, ri1, ri2};
        float dxy2 = A.dx*A.dx + A.dy*A.dy;
        #pragma unroll
        for (int k = 0; k < 3; ++k) {
            float is = __builtin_amdgcn_rcpf(ris[k].y * ris[k].y);
            float d2 = dxy2 + dzs[k]*dzs[k];
            float e  = __builtin_amdgcn_exp2f(d2 * is * C) + 2e-7f;
            if (!act) e = 0.0f;
            float gx = A.dx*is, gy = A.dy*is, gz = dzs[k]*is;
            float nu = e * ris[k].x;
            v[0] += e;
            v[1] += nu;
            v[2] += nu*gx;  v[3] += nu*gy;  v[4] += nu*gz;
            v[5] += e*gx;   v[6] += e*gy;   v[7] += e*gz;
        }
        red8_16(v);
        float ni  = v[0], nuA = v[1];
        float sx  = v[2], sy  = v[3], sz  = v[4];
        float sdx = v[5], sdy = v[6], sdz = v[7];

        float r   = __builtin_amdgcn_rcpf(ni);
        float rn  = ni * __builtin_amdgcn_rcpf(nuA);   // 1/n = norm/nu_s
        float in2 = r * r;
        float gx_ = (ni*sx - nuA*sdx) * in2;
        float gy_ = (ni*sy - nuA*sdy) * in2;
        float gz_ = (ni*sz - nuA*sdz) * in2;

        float dndx = gy_*M.drv[1] + gx_*M.drv[5] + gz_*M.drv[9]  + M.drv[13];
        float dndy = gy_*M.drv[0] + gx_*M.drv[4] + gz_*M.drv[8]  + M.drv[12];
        float dndz = gy_*M.drv[2] + gx_*M.drv[6] + gz_*M.drv[10] + M.drv[14];

        float dX2 = (dndx - dndz*dX) * (1.0f + dX*dX) * rn;
        float dY2 = (dndy - dndz*dY) * (1.0f + dY*dY) * rn;

        X = nX; Y = nY; z = nz;
        dX += dX2 * STEP;
        dY += dY2 * STEP;

        // LDS buffer instead of global store: keeps vmcnt queue loads-only
        if (nb == 0) { lX[s][rl] = X*2.0f - 1.0f; lY[s][rl] = Y*2.0f - 1.0f; }

        A = B;
    }

    __syncthreads();   // single wave: cheap; orders ds_writes before reads

    // bulk writeout: lane s stores this block's 4 rays as one float4 per array
    {
        const int s = tid;                     // 0..63
        const int ray0 = blockIdx.x * 4;
        float4 vx = *(const float4*)&lX[s][0];
        float4 vy = *(const float4*)&lY[s][0];
        *(float4*)&meshXT[s*NRAY2 + ray0] = vx;
        *(float4*)&meshYT[s*NRAY2 + ray0] = vy;
    }
}

// ---------------- kernel 2: fused resize + grid sample ----------------------
// Pack-of-4 version (unchanged from R8).
typedef _Float16 h16;
typedef _Float16 h16v4 __attribute__((ext_vector_type(4)));

__global__ __launch_bounds__(1024) void sample_kernel(
    const float* __restrict__ vol,      // 192^3
    const float* __restrict__ meshXT,   // (64, 4096)
    const float* __restrict__ meshYT,
    h16*   __restrict__ outTh,          // fp16 transposed out [c][a*192+b]
    float* __restrict__ outDirect,      // fallback fp32 out [a][b][c]
    int transposed)
{
    __shared__ h16    plane_h[PLANE];     // 73,728 B
    __shared__ float2 slice[64*64];       // 32,768 B

    const int tid = threadIdx.x;
    const int blk = blockIdx.x;
    const int c = (blk >> 3) + 24 * (blk & 7);   // consecutive c on same XCD

    const float D = 63.0f / 191.0f;

    {
        const float4* src = (const float4*)(vol + c * PLANE);
        h16v4* dst = (h16v4*)plane_h;
        #pragma unroll
        for (int k = 0; k < (PLANE/4)/1024; ++k) {
            float4 v = src[tid + k*1024];
            h16v4 hv = {(h16)v.x, (h16)v.y, (h16)v.z, (h16)v.w};
            dst[tid + k*1024] = hv;
        }
    }

    float ps = c * D;
    int s0 = min((int)ps, 62);
    float wcs = ps - (float)s0, wc0 = 1.0f - wcs;
    {
        const float* x0 = meshXT + s0*NRAY2;
        const float* x1 = meshXT + (s0+1)*NRAY2;
        const float* y0 = meshYT + s0*NRAY2;
        const float* y1 = meshYT + (s0+1)*NRAY2;
        #pragma unroll
        for (int k = 0; k < 4096/1024; ++k) {
            int t = tid + k*1024;
            slice[t] = make_float2(x0[t]*wc0 + x1[t]*wcs,
                                   y0[t]*wc0 + y1[t]*wcs);
        }
    }
    __syncthreads();

    #pragma unroll 1
    for (int k = 0; k < PLANE/4096; ++k) {        // 9 iterations
        const int w0 = (tid + k*1024) * 4;        // linear within plane
        const int a  = w0 / PHD;                  // pack stays in one row
        const int b0 = w0 - a*PHD;

        float pa = (float)a * D;
        int   i0 = min((int)pa, 62);
        float wa = pa - (float)i0;

        float pb0 = (float)b0 * D;
        int  jmin = min((int)pb0, 62);
        int  j2   = min(jmin + 2, 63);

        float2 r0c0 = slice[i0*64 + jmin];
        float2 r0c1 = slice[i0*64 + jmin + 1];
        float2 r0c2 = slice[i0*64 + j2];
        float2 r1c0 = slice[(i0+1)*64 + jmin];
        float2 r1c1 = slice[(i0+1)*64 + jmin + 1];
        float2 r1c2 = slice[(i0+1)*64 + j2];

        float c0x = r0c0.x + wa*(r1c0.x - r0c0.x);
        float c0y = r0c0.y + wa*(r1c0.y - r0c0.y);
        float c1x = r0c1.x + wa*(r1c1.x - r0c1.x);
        float c1y = r0c1.y + wa*(r1c1.y - r0c1.y);
        float c2x = r0c2.x + wa*(r1c2.x - r0c2.x);
        float c2y = r0c2.y + wa*(r1c2.y - r0c2.y);

        h16v4 res;
        #pragma unroll
        for (int m = 0; m < 4; ++m) {
            float pb = (float)(b0 + m) * D;
            int   j0 = min((int)pb, 62);
            float wb = pb - (float)j0;
            bool  hi = (j0 != jmin);

            float sax = hi ? c1x : c0x, say = hi ? c1y : c0y;
            float sbx = hi ? c2x : c1x, sby = hi ? c2y : c1y;
            float gx = sax + wb*(sbx - sax);
            float gy = say + wb*(sby - say);

            float ix = (gx + 1.0f) * 0.5f * 191.0f;
            float iy = (gy + 1.0f) * 0.5f * 191.0f;
            float x0f = floorf(ix); float fx = ix - x0f;
            float y0f = floorf(iy); float fy = iy - y0f;

            float acc = 0.0f;
            #pragma unroll
            for (int dyy = 0; dyy < 2; ++dyy) {
                #pragma unroll
                for (int dxx = 0; dxx < 2; ++dxx) {
                    float xi = x0f + (float)dxx;
                    float yi = y0f + (float)dyy;
                    bool inb = (xi >= 0.0f) && (xi <= 191.0f) &&
                               (yi >= 0.0f) && (yi <= 191.0f);
                    int xc = min(max((int)xi, 0), PHD - 1);
                    int yc = min(max((int)yi, 0), PHD - 1);
                    float w = (dxx ? fx : 1.0f - fx) * (dyy ? fy : 1.0f - fy);
                    float val = (float)plane_h[yc*PHD + xc];
                    acc += inb ? w * val : 0.0f;
                }
            }
            res[m] = (h16)acc;
        }

        if (transposed) {
            *(h16v4*)(outTh + (size_t)c*PLANE + w0) = res;   // 8 B contiguous
        } else {
            #pragma unroll
            for (int m = 0; m < 4; ++m)
                outDirect[(size_t)(a*PHD + b0 + m)*PHD + c] = (float)res[m];
        }
    }
}

// ---------------- kernel 3: (b,c) tile transpose, fp16 -> fp32 --------------
__global__ __launch_bounds__(256) void transpose_kernel(
    const h16* __restrict__ outTh, float* __restrict__ out)
{
    __shared__ h16 t[64][66];
    const int a  = blockIdx.z;
    const int b0 = blockIdx.x * 64;
    const int c0 = blockIdx.y * 64;
    const int tx = threadIdx.x & 63;
    const int ty = threadIdx.x >> 6;     // 0..3

    const h16* src = outTh + (size_t)(c0 + ty) * PLANE + a*PHD + b0 + tx;
    #pragma unroll
    for (int j = 0; j < 16; ++j)
        t[ty + 4*j][tx] = src[(size_t)(4*j) * PLANE];
    __syncthreads();

    float* dst = out + (size_t)a * PLANE + (size_t)(b0 + ty) * PHD + c0 + tx;
    #pragma unroll
    for (int j = 0; j < 16; ++j)
        dst[(size_t)(4*j) * PHD] = (float)t[tx][ty + 4*j];
}

// ---------------- launch -----------------------------------------------------
extern "C" void kernel_launch(void* const* d_in, const int* in_sizes, int n_in,
                              void* d_out, int out_size, void* d_ws, size_t ws_size,
                              hipStream_t stream)
{
    const float* Phantom = (const float*)d_in[0];   // 192^3
    const float* RI      = (const float*)d_in[1];   // (64^3, 2)
    const float* RayInit = (const float*)d_in[2];   // (4096, 5)
    float* out = (float*)d_out;

    float* meshXT = (float*)d_ws;                   // (64, 4096)   1 MB
    float* meshYT = meshXT + NRAY2 * NSAMP;         // (64, 4096)   1 MB
    h16*   outTh  = (h16*)(meshYT + NRAY2 * NSAMP); // 192^3 fp16   14.2 MB

    const size_t need = (size_t)(2 * NRAY2 * NSAMP) * sizeof(float)
                      + (size_t)PHD * PLANE * sizeof(h16);
    const int use_transpose = (ws_size >= need) ? 1 : 0;

    Mats M;
    build_mats(M);

    ray_trace_kernel<<<NRAY2/4, 64, 0, stream>>>(RI, RayInit, meshXT, meshYT, M);

    if (use_transpose) {
        sample_kernel<<<PHD, 1024, 0, stream>>>(Phantom, meshXT, meshYT,
                                                outTh, nullptr, 1);
        transpose_kernel<<<dim3(3, 3, PHD), 256, 0, stream>>>(outTh, out);
    } else {
        sample_kernel<<<PHD, 1024, 0, stream>>>(Phantom, meshXT, meshYT,
                                                nullptr, out, 0);
    }
}